// Round 7
// baseline (2827.993 us; speedup 1.0000x reference)
//
#include <hip/hip_runtime.h>

typedef unsigned short ushort;
typedef unsigned int uint;
typedef __bf16 bf16x8 __attribute__((ext_vector_type(8)));
typedef ushort ushort8 __attribute__((ext_vector_type(8)));
typedef float f32x4 __attribute__((ext_vector_type(4)));

#define Z4 f32x4{0.f, 0.f, 0.f, 0.f}

__device__ __forceinline__ f32x4 mfma16(bf16x8 a, bf16x8 b, f32x4 c) {
    return __builtin_amdgcn_mfma_f32_16x16x32_bf16(a, b, c, 0, 0, 0);
}
__device__ __forceinline__ float bf2f(ushort h) {
    union { uint u; float f; } v; v.u = ((uint)h) << 16; return v.f;
}
__device__ __forceinline__ ushort f2bf(float f) {  // RNE
    union { float f; uint u; } v; v.f = f;
    uint u = v.u;
    uint r = (u + 0x7fffu + ((u >> 16) & 1u)) >> 16;
    return (ushort)r;
}
__device__ __forceinline__ float sigmoidf_(float x) { return 1.f / (1.f + __expf(-x)); }
__device__ __forceinline__ float tanhf_(float x) {
    float e = __expf(2.f * x);
    return 1.f - 2.f / (e + 1.f);
}

typedef __attribute__((address_space(1))) uint guint;
typedef __attribute__((address_space(3))) uint luint;
__device__ __forceinline__ void dma16(const ushort* g, ushort* l) {
    __builtin_amdgcn_global_load_lds((const guint*)g, (luint*)l, 16, 0, 0);
}
template <int N> __device__ __forceinline__ void ring_wait() {
    asm volatile("s_waitcnt vmcnt(%0)" ::"n"(N) : "memory");
}
// raw barrier: LDS ordering only — does NOT drain the per-wave DMA ring (vmcnt)
__device__ __forceinline__ void wg_sync() {
    asm volatile("s_waitcnt lgkmcnt(0)\n\ts_barrier" ::: "memory");
}

// ---------------------------------------------------------------------------
// Weight pre-pack, MFMA-B fragment-major: frag F = ntile*(K/32)+kf, 1 KB each.
// ---------------------------------------------------------------------------
__global__ void pack_direct_k(const float* __restrict__ src, ushort* __restrict__ dst,
                              int N, int K) {  // src row-major [N,K]
    int total = (N >> 4) * (K >> 5) * 64;
    int idx = blockIdx.x * 256 + threadIdx.x;
    if (idx >= total) return;
    int l = idx & 63, f = idx >> 6;
    int kfrags = K >> 5;
    int nt = f / kfrags, kf = f - nt * kfrags;
    int n = nt * 16 + (l & 15);
    int k0 = kf * 32 + (l >> 4) * 8;
    const float* s = src + (size_t)n * K + k0;
    ushort8 u;
#pragma unroll
    for (int j = 0; j < 8; j++) u[j] = f2bf(s[j]);
    *(ushort8*)&dst[(size_t)f * 512 + l * 8] = u;
}
__global__ void pack_trans_k(const float* __restrict__ src, ushort* __restrict__ dst,
                             int N, int K) {  // src row-major [K,N]
    int total = (N >> 4) * (K >> 5) * 64;
    int idx = blockIdx.x * 256 + threadIdx.x;
    if (idx >= total) return;
    int l = idx & 63, f = idx >> 6;
    int kfrags = K >> 5;
    int nt = f / kfrags, kf = f - nt * kfrags;
    int n = nt * 16 + (l & 15);
    int k0 = kf * 32 + (l >> 4) * 8;
    ushort8 u;
#pragma unroll
    for (int j = 0; j < 8; j++) u[j] = f2bf(src[(size_t)(k0 + j) * N + n]);
    *(ushort8*)&dst[(size_t)f * 512 + l * 8] = u;
}

// ---------------------------------------------------------------------------
// Fused MLP: X2 = relu(H@W1+b1)@W2+b2  -> bf16 [65536,256]
// ---------------------------------------------------------------------------
__global__ __launch_bounds__(256) void mlp_kernel(
    const float* __restrict__ H,     // [65536,128] fp32
    const ushort* __restrict__ W1P,  // packed N=512,K=128
    const float* __restrict__ b1,
    const ushort* __restrict__ W2P,  // packed N=256,K=512
    const float* __restrict__ b2,
    ushort* __restrict__ X2)         // [65536,256] bf16
{
    __shared__ __align__(16) ushort sH[64][136];
    __shared__ __align__(16) ushort sT[64][264];
    __shared__ float sb1[512], sb2[256];
    const int tid = threadIdx.x;
    const int w = tid >> 6, lane = tid & 63;
    const int q = lane >> 4, tc = lane & 15;
    const int lo8 = lane * 8;
    const int m0 = blockIdx.x * 64;

    {   // stage H 64x128 fp32 -> bf16
        int r = tid >> 2, c0 = (tid & 3) * 32;
        const float* src = H + (size_t)(m0 + r) * 128 + c0;
#pragma unroll
        for (int v = 0; v < 4; v++) {
            float4 a = *(const float4*)(src + v * 8);
            float4 b = *(const float4*)(src + v * 8 + 4);
            ushort8 u;
            u[0] = f2bf(a.x); u[1] = f2bf(a.y); u[2] = f2bf(a.z); u[3] = f2bf(a.w);
            u[4] = f2bf(b.x); u[5] = f2bf(b.y); u[6] = f2bf(b.z); u[7] = f2bf(b.w);
            *(ushort8*)&sH[r][c0 + v * 8] = u;
        }
    }
    for (int i = tid; i < 512; i += 256) sb1[i] = b1[i];
    if (tid < 256) sb2[tid] = b2[tid];
    __syncthreads();

    bf16x8 af[4];
#pragma unroll
    for (int kb = 0; kb < 4; kb++) af[kb] = *(const bf16x8*)&sH[w * 16 + tc][kb * 32 + q * 8];

    f32x4 accH[16];
#pragma unroll
    for (int nt = 0; nt < 16; nt++) accH[nt] = Z4;

#pragma unroll 1
    for (int half = 0; half < 2; half++) {
        __syncthreads();  // protect sT reuse across halves
#pragma unroll
        for (int j = 0; j < 16; j++) {
            int n = half * 256 + j * 16 + tc;
            const ushort* bp = W1P + (size_t)((half * 16 + j) * 4) * 512 + lo8;
            f32x4 a = Z4;
#pragma unroll
            for (int kb = 0; kb < 4; kb++)
                a = mfma16(af[kb], *(const bf16x8*)(bp + kb * 512), a);
            float bv = sb1[n];
#pragma unroll
            for (int i = 0; i < 4; i++)
                sT[w * 16 + q * 4 + i][j * 16 + tc] = f2bf(fmaxf(a[i] + bv, 0.f));
        }
        __syncthreads();

        bf16x8 a2[8];
#pragma unroll
        for (int kb = 0; kb < 8; kb++) a2[kb] = *(const bf16x8*)&sT[w * 16 + tc][kb * 32 + q * 8];
#pragma unroll
        for (int nt = 0; nt < 16; nt++) {
            const ushort* bp = W2P + (size_t)(nt * 16 + half * 8) * 512 + lo8;
#pragma unroll
            for (int kb = 0; kb < 8; kb++)
                accH[nt] = mfma16(a2[kb], *(const bf16x8*)(bp + kb * 512), accH[nt]);
        }
    }

#pragma unroll
    for (int nt = 0; nt < 16; nt++) {
        int col = nt * 16 + tc;
        float bv = sb2[col];
#pragma unroll
        for (int i = 0; i < 4; i++)
            X2[(size_t)(m0 + w * 16 + q * 4 + i) * 256 + col] = f2bf(accH[nt][i] + bv);
    }
}

// ---------------------------------------------------------------------------
// GEMM, packed-B: C = A @ B^T + bias.  A bf16 row-major [M,K], BP packed.
// mode 0: bf16 row-major out; 1: fp32 row-major out; 2: bf16 Xg-swizzle out
// ---------------------------------------------------------------------------
__global__ __launch_bounds__(256) void gemm128P(
    const ushort* __restrict__ A, const ushort* __restrict__ BP,
    const float* __restrict__ bias, void* __restrict__ Cout,
    int M, int N, int K, int mode)
{
    __shared__ __align__(16) ushort sA[128][40];
    const int tid = threadIdx.x;
    const int lane = tid & 63, wid = tid >> 6;
    const int q = lane >> 4, tc = lane & 15;
    const int lo8 = lane * 8;
    const int wm = (wid >> 1) * 64, wn = (wid & 1) * 64;
    const int bm = blockIdx.y * 128, bn = blockIdx.x * 128;

    f32x4 acc[4][4];
#pragma unroll
    for (int im = 0; im < 4; im++)
#pragma unroll
        for (int in_ = 0; in_ < 4; in_++) acc[im][in_] = Z4;

    const int arow = tid >> 1, acol = (tid & 1) * 16;
    const int kfrags = K >> 5;

    for (int kc = 0; kc < K; kc += 32) {
        const ushort* ga = A + (size_t)(bm + arow) * K + kc + acol;
        ushort8 va0 = *(const ushort8*)ga;
        ushort8 va1 = *(const ushort8*)(ga + 8);
        __syncthreads();
        *(ushort8*)&sA[arow][acol] = va0;
        *(ushort8*)&sA[arow][acol + 8] = va1;
        __syncthreads();

        bf16x8 af[4], bf[4];
#pragma unroll
        for (int im = 0; im < 4; im++) af[im] = *(const bf16x8*)&sA[wm + im * 16 + tc][q * 8];
#pragma unroll
        for (int in_ = 0; in_ < 4; in_++) {
            int nt = ((bn + wn) >> 4) + in_;
            bf[in_] = *(const bf16x8*)(BP + (size_t)(nt * kfrags + (kc >> 5)) * 512 + lo8);
        }
#pragma unroll
        for (int im = 0; im < 4; im++)
#pragma unroll
            for (int in_ = 0; in_ < 4; in_++)
                acc[im][in_] = mfma16(af[im], bf[in_], acc[im][in_]);
    }

#pragma unroll
    for (int in_ = 0; in_ < 4; in_++) {
        int col = bn + wn + in_ * 16 + tc;
        float bv = bias[col];
#pragma unroll
        for (int im = 0; im < 4; im++) {
            int row0 = bm + wm + im * 16 + q * 4;
#pragma unroll
            for (int r = 0; r < 4; r++) {
                float v = acc[im][in_][r] + bv;
                int row = row0 + r;
                if (mode == 0) {
                    ((ushort*)Cout)[(size_t)row * N + col] = f2bf(v);
                } else if (mode == 1) {
                    ((float*)Cout)[(size_t)row * N + col] = v;
                } else {
                    int b = row >> 7, t = row & 127;
                    size_t dst = (((size_t)(b >> 4) * 128 + t) * N + col) * 16 + (b & 15);
                    ((ushort*)Cout)[dst] = f2bf(v);
                }
            }
        }
    }
}

// ---------------------------------------------------------------------------
// Sequential scan, v7 = v6 + three register-neutral cuts:
//  (1) XOR-swizzled UNPADDED h_bf/rh_bf[16][256]: every access uses
//      col ^ ((row&7)<<3) (ushort units).  Old [264] layout gave b128
//      A-frag reads bank group 4(tc+q)%32 = 8 lanes / 4-bank cluster (4x the
//      floor) -> 4.6e7 conflict cycles/dispatch.  Swizzled group =
//      (4k+q)^(tc&7): uniform 8 accesses/bank = HW floor.  Write swizzles
//      are thread-constant (hoisted).
//  (2) ring 4 slots/wave (128 KB): prefetch distance 3 chunks.  Waits:
//      prologue 4 pumps; first wait<6> drains store+xg*3+chunk0 (12 out);
//      steady <6> (4 chunks = 8 loads out); GRU tail J=9,10,11 -> <4>,<2>,<0>.
//  (3) gate-major Whh chunks (g=J>>2, kc=J&3): pump address is shift/mask
//      only (was runtime %3 and /3).  Per-gate kf order still 0..7 ascending
//      -> bit-identical output.
// Everything else identical to v6 (64 WGs x 8 rows, 16 waves, lane-rebalanced
// epilogues, wOr/wOz persistent in AGPR, VGPR+AGPR = 128 = 4 waves/SIMD cap).
// ---------------------------------------------------------------------------
__global__ __launch_bounds__(1024) void scan_fused(
    const ushort* __restrict__ XgSw,  // [32][128][768][16] bf16 swizzled
    const ushort* __restrict__ OhrP, const ushort* __restrict__ OhzP,
    const ushort* __restrict__ OhhP,  // packed N=256,K=256
    const ushort* __restrict__ WhhP,  // packed N=768,K=256
    const float*  __restrict__ bhh,   // [768]
    ushort* __restrict__ hseq)        // [65536,256] bf16, row = b*128+t
{
    const int bx = blockIdx.x;        // 64 WGs x 8 rows
    const int m0 = bx * 8;
    const int tid = threadIdx.x;
    const int w = tid >> 6, lane = tid & 63;   // 16 waves
    const int q = lane >> 4, tc = lane & 15;
    const int lo8 = lane * 8;
    const int colbase = w * 16 + tc;           // this wave's ntile = w
    const int R = ((lane >> 4) & 1) * 4 + ((lane >> 5) << 1);  // balanced row
    const bool lo = (q < 2);
    const int rsw = (tc & 7) << 3;                      // read-row swizzle
    const int wc0 = colbase ^ ((R & 7) << 3);           // write col, row R
    const int wc1 = colbase ^ (((R + 1) & 7) << 3);     // write col, row R+1

    __shared__ __align__(16) ushort ring[16][4][1024];  // 128 KB (2 KB/slot)
    __shared__ __align__(16) ushort h_bf[16][256];      // 8 KB, swizzled
    __shared__ __align__(16) ushort rh_bf[16][256];     // 8 KB, swizzled

    for (int i = tid; i < 16 * 256; i += 1024) (&h_bf[0][0])[i] = 0;
    for (int i = tid; i < 16 * 256; i += 1024) (&rh_bf[0][0])[i] = 0;

    // per-thread biases (1 ntile -> scalars; same for both balanced rows)
    float rbv = bhh[colbase], zbv = bhh[256 + colbase], hnbv = bhh[512 + colbase];

    // persistent ODE r/z weights, this wave's ntile: 16 frags = 64 regs
    bf16x8 wOr[8], wOz[8];
#pragma unroll
    for (int f = 0; f < 8; f++) {
        wOr[f] = *(const bf16x8*)(OhrP + (size_t)(w * 8 + f) * 512 + lo8);
        wOz[f] = *(const bf16x8*)(OhzP + (size_t)(w * 8 + f) * 512 + lo8);
    }

    float hreg[2] = {0.f, 0.f};  // balanced rows R, R+1

    // hoisted store-phase source (swizzled) and destination column
    const int srow = tid >> 7, scol = (tid & 127) * 2;
    const ushort* s_src = &h_bf[srow][scol ^ ((srow & 7) << 3)];

    int ic = 0, islot = 0, slot = 0;
    auto pump = [&]() {
        if (ic >= 28) return;
        asm volatile("s_waitcnt lgkmcnt(0)" ::: "memory");  // slot-reuse fence
        const ushort* g;
        if (ic < 16) {
            g = OhhP + (size_t)(w * 8 + (ic & 3) * 2) * 512;
        } else {
            int j = ic - 16, gg = j >> 2, kc = j & 3;   // gate-major: cheap
            g = WhhP + (size_t)((gg * 16 + w) * 8 + kc * 2) * 512;
        }
        g += lo8;
        ushort* sb = &ring[w][islot][0];
        dma16(g, sb); dma16(g + 512, sb + 512);
        ic++; islot = (islot + 1) & 3;
    };

    __syncthreads();  // zero-fill visible (no DMA yet)

#pragma unroll 1
    for (int t = 0; t < 128; t++) {
        // x-gates: 2 balanced rows per thread -> 3 x uint (rows R, R+1)
        const ushort* xgp = XgSw + (((size_t)(bx >> 1) * 128 + t) * 768) * 16
                            + (bx & 1) * 8 + R;
        uint xg[3];
#pragma unroll
        for (int g = 0; g < 3; g++)
            xg[g] = *(const uint*)(xgp + (size_t)(g * 256 + colbase) * 16);

        ic = 0; islot = 0; slot = 0;
        pump(); pump(); pump(); pump();

        // ---- 4 Euler ODE substeps ----
#pragma unroll 1
        for (int s = 0; s < 4; s++) {
            f32x4 ar = Z4, az = Z4;
#pragma unroll
            for (int kh = 0; kh < 2; kh++) {
                bf16x8 af[4];
#pragma unroll
                for (int k = 0; k < 4; k++)
                    af[k] = *(const bf16x8*)&h_bf[tc][((kh * 4 + k) * 32 + q * 8) ^ rsw];
#pragma unroll
                for (int k = 0; k < 4; k++) {
                    ar = mfma16(af[k], wOr[kh * 4 + k], ar);
                    az = mfma16(af[k], wOz[kh * 4 + k], az);
                }
            }
            // rebalance ar/az: lane>=32 takes elems {2,3} of lane-32
            float ar2 = __shfl(ar[2], lane & 31), ar3 = __shfl(ar[3], lane & 31);
            float az2 = __shfl(az[2], lane & 31), az3 = __shfl(az[3], lane & 31);
            float ea0 = lo ? ar[0] : ar2, ea1 = lo ? ar[1] : ar3;
            float ez0 = lo ? az[0] : az2, ez1 = lo ? az[1] : az3;
            rh_bf[R + 0][wc0] = f2bf(sigmoidf_(ea0) * hreg[0]);
            rh_bf[R + 1][wc1] = f2bf(sigmoidf_(ea1) * hreg[1]);
            wg_sync();  // rh ready

            f32x4 uu = Z4;
#pragma unroll
            for (int cc = 0; cc < 4; cc++) {  // chunk cc: kf pair {2cc, 2cc+1}
                bf16x8 au0 = *(const bf16x8*)&rh_bf[tc][((cc * 2) * 32 + q * 8) ^ rsw];
                bf16x8 au1 = *(const bf16x8*)&rh_bf[tc][((cc * 2 + 1) * 32 + q * 8) ^ rsw];
                ring_wait<6>();
                const ushort* sb = &ring[w][slot][0] + lo8;
                bf16x8 v0 = *(const bf16x8*)(sb);
                bf16x8 v1 = *(const bf16x8*)(sb + 512);
                slot = (slot + 1) & 3;
                pump();
                uu = mfma16(au0, v0, uu);
                uu = mfma16(au1, v1, uu);
            }
            // rebalance uu; z already balanced (ez0/ez1)
            float uu2 = __shfl(uu[2], lane & 31), uu3 = __shfl(uu[3], lane & 31);
            float eu0 = lo ? uu[0] : uu2, eu1 = lo ? uu[1] : uu3;
            {
                float zv = sigmoidf_(ez0), hv = hreg[0];
                float hn = hv + 0.25f * (1.f - zv) * (tanhf_(eu0) - hv);
                hreg[0] = hn;
                h_bf[R + 0][wc0] = f2bf(hn);
            }
            {
                float zv = sigmoidf_(ez1), hv = hreg[1];
                float hn = hv + 0.25f * (1.f - zv) * (tanhf_(eu1) - hv);
                hreg[1] = hn;
                h_bf[R + 1][wc1] = f2bf(hn);
            }
            wg_sync();  // h ready
        }

        // ---- GRU h-part: Whh, 12 chunks, gate-major (g=J>>2, kc=J&3) ----
        f32x4 accr = Z4, accz = Z4, accn = Z4;
#define GRU_CHUNK(J, WN)                                                       \
        {                                                                      \
            constexpr int g_ = (J) >> 2, kc_ = (J) & 3;                        \
            bf16x8 ah0 = *(const bf16x8*)&h_bf[tc][((kc_ * 2) * 32 + q * 8) ^ rsw];     \
            bf16x8 ah1 = *(const bf16x8*)&h_bf[tc][((kc_ * 2 + 1) * 32 + q * 8) ^ rsw]; \
            ring_wait<WN>();                                                   \
            const ushort* sb = &ring[w][slot][0] + lo8;                        \
            bf16x8 v0 = *(const bf16x8*)(sb);                                  \
            bf16x8 v1 = *(const bf16x8*)(sb + 512);                            \
            slot = (slot + 1) & 3;                                             \
            pump();                                                            \
            f32x4* tg = (g_ == 0) ? &accr : (g_ == 1) ? &accz : &accn;         \
            *tg = mfma16(ah0, v0, *tg);                                        \
            *tg = mfma16(ah1, v1, *tg);                                        \
        }
        GRU_CHUNK(0, 6)  GRU_CHUNK(1, 6)  GRU_CHUNK(2, 6)  GRU_CHUNK(3, 6)
        GRU_CHUNK(4, 6)  GRU_CHUNK(5, 6)  GRU_CHUNK(6, 6)  GRU_CHUNK(7, 6)
        GRU_CHUNK(8, 6)  GRU_CHUNK(9, 4)  GRU_CHUNK(10, 2) GRU_CHUNK(11, 0)
#undef GRU_CHUNK
        wg_sync();  // all h_bf reads done

        // ---- GRU epilogue, balanced (2 elems/thread) ----
        {
            float r2 = __shfl(accr[2], lane & 31), r3 = __shfl(accr[3], lane & 31);
            float z2 = __shfl(accz[2], lane & 31), z3 = __shfl(accz[3], lane & 31);
            float n2 = __shfl(accn[2], lane & 31), n3 = __shfl(accn[3], lane & 31);
            float er0 = lo ? accr[0] : r2, er1 = lo ? accr[1] : r3;
            float ez0 = lo ? accz[0] : z2, ez1 = lo ? accz[1] : z3;
            float en0 = lo ? accn[0] : n2, en1 = lo ? accn[1] : n3;
            {
                float xr = bf2f((ushort)(xg[0])), xz = bf2f((ushort)(xg[1])),
                      xn = bf2f((ushort)(xg[2]));
                float rg = sigmoidf_(er0 + xr + rbv);
                float zg = sigmoidf_(ez0 + xz + zbv);
                float ng = tanhf_(xn + rg * (en0 + hnbv));
                float hv = hreg[0];
                float hn = (1.f - zg) * ng + zg * hv;
                hreg[0] = hn;
                h_bf[R + 0][wc0] = f2bf(hn);
            }
            {
                float xr = bf2f((ushort)(xg[0] >> 16)), xz = bf2f((ushort)(xg[1] >> 16)),
                      xn = bf2f((ushort)(xg[2] >> 16));
                float rg = sigmoidf_(er1 + xr + rbv);
                float zg = sigmoidf_(ez1 + xz + zbv);
                float ng = tanhf_(xn + rg * (en1 + hnbv));
                float hv = hreg[1];
                float hn = (1.f - zg) * ng + zg * hv;
                hreg[1] = hn;
                h_bf[R + 1][wc1] = f2bf(hn);
            }
        }
        wg_sync();  // h_new visible

        // ---- coalesced h store: 8 rows x 256 cols, 1 uint per thread ----
        *(uint*)&hseq[((size_t)(m0 + srow) * 128 + t) * 256 + scol] =
            *(const uint*)s_src;
    }
}

// ---------------------------------------------------------------------------
// Launch.  Workspace 129.6 MB:
//   [0, 100663296)            Xg swizzled [32][128][768][16] bf16
//   [100663296, 134217728)    X2 [65536,256] bf16  (aliased by hseq after use)
//   [134217728, ...)          packed weights (1.44 MB)
// ---------------------------------------------------------------------------
extern "C" void kernel_launch(void* const* d_in, const int* in_sizes, int n_in,
                              void* d_out, int out_size, void* d_ws, size_t ws_size,
                              hipStream_t stream) {
    const float* H   = (const float*)d_in[0];
    const float* W1  = (const float*)d_in[2];
    const float* b1  = (const float*)d_in[3];
    const float* W2  = (const float*)d_in[4];
    const float* b2  = (const float*)d_in[5];
    const float* Ohr = (const float*)d_in[6];
    const float* Ohz = (const float*)d_in[7];
    const float* Ohh = (const float*)d_in[8];
    const float* Wih = (const float*)d_in[9];
    const float* Whh = (const float*)d_in[10];
    const float* bih = (const float*)d_in[11];
    const float* bhh = (const float*)d_in[12];
    const float* Wr  = (const float*)d_in[13];
    const float* br  = (const float*)d_in[14];
    float* out = (float*)d_out;
    char* ws = (char*)d_ws;

    ushort* Xg   = (ushort*)(ws);
    ushort* X2   = (ushort*)(ws + 100663296);
    ushort* hseq = X2;  // alias: X2 dead before scan writes hseq
    char* pk = ws + 134217728;
    ushort* W1P  = (ushort*)(pk);
    ushort* W2P  = (ushort*)(pk + 131072);
    ushort* WrP  = (ushort*)(pk + 393216);
    ushort* OhrP = (ushort*)(pk + 458752);
    ushort* OhzP = (ushort*)(pk + 589824);
    ushort* OhhP = (ushort*)(pk + 720896);
    ushort* WihP = (ushort*)(pk + 851968);
    // end at +1245184

    pack_trans_k<<<dim3(32),  256, 0, stream>>>(W1,  W1P, 512, 128);
    pack_trans_k<<<dim3(64),  256, 0, stream>>>(W2,  W2P, 256, 512);
    pack_trans_k<<<dim3(16),  256, 0, stream>>>(Wr,  WrP, 128, 256);
    pack_direct_k<<<dim3(32), 256, 0, stream>>>(Ohr, OhrP, 256, 256);
    pack_direct_k<<<dim3(32), 256, 0, stream>>>(Ohz, OhzP, 256, 256);
    pack_direct_k<<<dim3(32), 256, 0, stream>>>(Ohh, OhhP, 256, 256);
    pack_direct_k<<<dim3(96), 256, 0, stream>>>(Wih, WihP, 768, 256);
    pack_direct_k<<<dim3(96), 256, 0, stream>>>(Whh, (ushort*)(pk + 1245184), 768, 256);
    ushort* WhhP = (ushort*)(pk + 1245184);

    // Phase A: X2 = MLP(H); Xg = X2 @ Wih^T + bih (swizzled for the scan)
    mlp_kernel<<<dim3(1024), 256, 0, stream>>>(H, W1P, b1, W2P, b2, X2);
    gemm128P<<<dim3(6, 512), 256, 0, stream>>>(X2, WihP, bih, Xg, 65536, 768, 256, 2);

    // Phase B: sequential scan -> hseq (64 WGs x 8 rows, 16 waves each)
    scan_fused<<<dim3(64), 1024, 0, stream>>>(Xg, OhrP, OhzP, OhhP, WhhP, bhh, hseq);

    // Phase C: out = hseq @ Wr + br (fp32)
    gemm128P<<<dim3(1, 512), 256, 0, stream>>>(hseq, WrP, br, out, 65536, 128, 256, 1);
}

// Round 8
// 2524.567 us; speedup vs baseline: 1.1202x; 1.1202x over previous
//
#include <hip/hip_runtime.h>

typedef unsigned short ushort;
typedef unsigned int uint;
typedef __bf16 bf16x8 __attribute__((ext_vector_type(8)));
typedef ushort ushort8 __attribute__((ext_vector_type(8)));
typedef float f32x4 __attribute__((ext_vector_type(4)));

#define Z4 f32x4{0.f, 0.f, 0.f, 0.f}

__device__ __forceinline__ f32x4 mfma16(bf16x8 a, bf16x8 b, f32x4 c) {
    return __builtin_amdgcn_mfma_f32_16x16x32_bf16(a, b, c, 0, 0, 0);
}
__device__ __forceinline__ float bf2f(ushort h) {
    union { uint u; float f; } v; v.u = ((uint)h) << 16; return v.f;
}
__device__ __forceinline__ ushort f2bf(float f) {  // RNE
    union { float f; uint u; } v; v.f = f;
    uint u = v.u;
    uint r = (u + 0x7fffu + ((u >> 16) & 1u)) >> 16;
    return (ushort)r;
}
__device__ __forceinline__ float sigmoidf_(float x) { return 1.f / (1.f + __expf(-x)); }
__device__ __forceinline__ float tanhf_(float x) {
    float e = __expf(2.f * x);
    return 1.f - 2.f / (e + 1.f);
}

typedef __attribute__((address_space(1))) uint guint;
typedef __attribute__((address_space(3))) uint luint;
__device__ __forceinline__ void dma16(const ushort* g, ushort* l) {
    __builtin_amdgcn_global_load_lds((const guint*)g, (luint*)l, 16, 0, 0);
}
template <int N> __device__ __forceinline__ void ring_wait() {
    asm volatile("s_waitcnt vmcnt(%0)" ::"n"(N) : "memory");
}
// raw barrier: LDS ordering only — does NOT drain the per-wave DMA ring (vmcnt)
__device__ __forceinline__ void wg_sync() {
    asm volatile("s_waitcnt lgkmcnt(0)\n\ts_barrier" ::: "memory");
}

// ---------------------------------------------------------------------------
// Weight pre-pack, MFMA-B fragment-major: frag F = ntile*(K/32)+kf, 1 KB each.
// ---------------------------------------------------------------------------
__global__ void pack_direct_k(const float* __restrict__ src, ushort* __restrict__ dst,
                              int N, int K) {  // src row-major [N,K]
    int total = (N >> 4) * (K >> 5) * 64;
    int idx = blockIdx.x * 256 + threadIdx.x;
    if (idx >= total) return;
    int l = idx & 63, f = idx >> 6;
    int kfrags = K >> 5;
    int nt = f / kfrags, kf = f - nt * kfrags;
    int n = nt * 16 + (l & 15);
    int k0 = kf * 32 + (l >> 4) * 8;
    const float* s = src + (size_t)n * K + k0;
    ushort8 u;
#pragma unroll
    for (int j = 0; j < 8; j++) u[j] = f2bf(s[j]);
    *(ushort8*)&dst[(size_t)f * 512 + l * 8] = u;
}
__global__ void pack_trans_k(const float* __restrict__ src, ushort* __restrict__ dst,
                             int N, int K) {  // src row-major [K,N]
    int total = (N >> 4) * (K >> 5) * 64;
    int idx = blockIdx.x * 256 + threadIdx.x;
    if (idx >= total) return;
    int l = idx & 63, f = idx >> 6;
    int kfrags = K >> 5;
    int nt = f / kfrags, kf = f - nt * kfrags;
    int n = nt * 16 + (l & 15);
    int k0 = kf * 32 + (l >> 4) * 8;
    ushort8 u;
#pragma unroll
    for (int j = 0; j < 8; j++) u[j] = f2bf(src[(size_t)(k0 + j) * N + n]);
    *(ushort8*)&dst[(size_t)f * 512 + l * 8] = u;
}

// ---------------------------------------------------------------------------
// Fused MLP: X2 = relu(H@W1+b1)@W2+b2  -> bf16 [65536,256]
// ---------------------------------------------------------------------------
__global__ __launch_bounds__(256) void mlp_kernel(
    const float* __restrict__ H,     // [65536,128] fp32
    const ushort* __restrict__ W1P,  // packed N=512,K=128
    const float* __restrict__ b1,
    const ushort* __restrict__ W2P,  // packed N=256,K=512
    const float* __restrict__ b2,
    ushort* __restrict__ X2)         // [65536,256] bf16
{
    __shared__ __align__(16) ushort sH[64][136];
    __shared__ __align__(16) ushort sT[64][264];
    __shared__ float sb1[512], sb2[256];
    const int tid = threadIdx.x;
    const int w = tid >> 6, lane = tid & 63;
    const int q = lane >> 4, tc = lane & 15;
    const int lo8 = lane * 8;
    const int m0 = blockIdx.x * 64;

    {   // stage H 64x128 fp32 -> bf16
        int r = tid >> 2, c0 = (tid & 3) * 32;
        const float* src = H + (size_t)(m0 + r) * 128 + c0;
#pragma unroll
        for (int v = 0; v < 4; v++) {
            float4 a = *(const float4*)(src + v * 8);
            float4 b = *(const float4*)(src + v * 8 + 4);
            ushort8 u;
            u[0] = f2bf(a.x); u[1] = f2bf(a.y); u[2] = f2bf(a.z); u[3] = f2bf(a.w);
            u[4] = f2bf(b.x); u[5] = f2bf(b.y); u[6] = f2bf(b.z); u[7] = f2bf(b.w);
            *(ushort8*)&sH[r][c0 + v * 8] = u;
        }
    }
    for (int i = tid; i < 512; i += 256) sb1[i] = b1[i];
    if (tid < 256) sb2[tid] = b2[tid];
    __syncthreads();

    bf16x8 af[4];
#pragma unroll
    for (int kb = 0; kb < 4; kb++) af[kb] = *(const bf16x8*)&sH[w * 16 + tc][kb * 32 + q * 8];

    f32x4 accH[16];
#pragma unroll
    for (int nt = 0; nt < 16; nt++) accH[nt] = Z4;

#pragma unroll 1
    for (int half = 0; half < 2; half++) {
        __syncthreads();  // protect sT reuse across halves
#pragma unroll
        for (int j = 0; j < 16; j++) {
            int n = half * 256 + j * 16 + tc;
            const ushort* bp = W1P + (size_t)((half * 16 + j) * 4) * 512 + lo8;
            f32x4 a = Z4;
#pragma unroll
            for (int kb = 0; kb < 4; kb++)
                a = mfma16(af[kb], *(const bf16x8*)(bp + kb * 512), a);
            float bv = sb1[n];
#pragma unroll
            for (int i = 0; i < 4; i++)
                sT[w * 16 + q * 4 + i][j * 16 + tc] = f2bf(fmaxf(a[i] + bv, 0.f));
        }
        __syncthreads();

        bf16x8 a2[8];
#pragma unroll
        for (int kb = 0; kb < 8; kb++) a2[kb] = *(const bf16x8*)&sT[w * 16 + tc][kb * 32 + q * 8];
#pragma unroll
        for (int nt = 0; nt < 16; nt++) {
            const ushort* bp = W2P + (size_t)(nt * 16 + half * 8) * 512 + lo8;
#pragma unroll
            for (int kb = 0; kb < 8; kb++)
                accH[nt] = mfma16(a2[kb], *(const bf16x8*)(bp + kb * 512), accH[nt]);
        }
    }

#pragma unroll
    for (int nt = 0; nt < 16; nt++) {
        int col = nt * 16 + tc;
        float bv = sb2[col];
#pragma unroll
        for (int i = 0; i < 4; i++)
            X2[(size_t)(m0 + w * 16 + q * 4 + i) * 256 + col] = f2bf(accH[nt][i] + bv);
    }
}

// ---------------------------------------------------------------------------
// GEMM, packed-B: C = A @ B^T + bias.  A bf16 row-major [M,K], BP packed.
// mode 0: bf16 row-major out; 1: fp32 row-major out; 2: bf16 Xg-swizzle out
// ---------------------------------------------------------------------------
__global__ __launch_bounds__(256) void gemm128P(
    const ushort* __restrict__ A, const ushort* __restrict__ BP,
    const float* __restrict__ bias, void* __restrict__ Cout,
    int M, int N, int K, int mode)
{
    __shared__ __align__(16) ushort sA[128][40];
    const int tid = threadIdx.x;
    const int lane = tid & 63, wid = tid >> 6;
    const int q = lane >> 4, tc = lane & 15;
    const int lo8 = lane * 8;
    const int wm = (wid >> 1) * 64, wn = (wid & 1) * 64;
    const int bm = blockIdx.y * 128, bn = blockIdx.x * 128;

    f32x4 acc[4][4];
#pragma unroll
    for (int im = 0; im < 4; im++)
#pragma unroll
        for (int in_ = 0; in_ < 4; in_++) acc[im][in_] = Z4;

    const int arow = tid >> 1, acol = (tid & 1) * 16;
    const int kfrags = K >> 5;

    for (int kc = 0; kc < K; kc += 32) {
        const ushort* ga = A + (size_t)(bm + arow) * K + kc + acol;
        ushort8 va0 = *(const ushort8*)ga;
        ushort8 va1 = *(const ushort8*)(ga + 8);
        __syncthreads();
        *(ushort8*)&sA[arow][acol] = va0;
        *(ushort8*)&sA[arow][acol + 8] = va1;
        __syncthreads();

        bf16x8 af[4], bf[4];
#pragma unroll
        for (int im = 0; im < 4; im++) af[im] = *(const bf16x8*)&sA[wm + im * 16 + tc][q * 8];
#pragma unroll
        for (int in_ = 0; in_ < 4; in_++) {
            int nt = ((bn + wn) >> 4) + in_;
            bf[in_] = *(const bf16x8*)(BP + (size_t)(nt * kfrags + (kc >> 5)) * 512 + lo8);
        }
#pragma unroll
        for (int im = 0; im < 4; im++)
#pragma unroll
            for (int in_ = 0; in_ < 4; in_++)
                acc[im][in_] = mfma16(af[im], bf[in_], acc[im][in_]);
    }

#pragma unroll
    for (int in_ = 0; in_ < 4; in_++) {
        int col = bn + wn + in_ * 16 + tc;
        float bv = bias[col];
#pragma unroll
        for (int im = 0; im < 4; im++) {
            int row0 = bm + wm + im * 16 + q * 4;
#pragma unroll
            for (int r = 0; r < 4; r++) {
                float v = acc[im][in_][r] + bv;
                int row = row0 + r;
                if (mode == 0) {
                    ((ushort*)Cout)[(size_t)row * N + col] = f2bf(v);
                } else if (mode == 1) {
                    ((float*)Cout)[(size_t)row * N + col] = v;
                } else {
                    int b = row >> 7, t = row & 127;
                    size_t dst = (((size_t)(b >> 4) * 128 + t) * N + col) * 16 + (b & 15);
                    ((ushort*)Cout)[dst] = f2bf(v);
                }
            }
        }
    }
}

// ---------------------------------------------------------------------------
// Sequential scan, v8 = v6 (the proven best) + two register-neutral cuts.
// v7 post-mortem: swizzle was a NO-OP (conflict counter identical 4.61e7 —
// v6's [264] layout was already at the b128 8-access/bank floor) and its
// per-read XOR + 4-slot ring cost 15%.  Reverted.
// v8 changes vs v6:
//  (1) ZERO-ROW BROADCAST: M=8, so A-fragment rows 8-15 are structurally
//      zero.  Buffers shrink to h_bf/rh_bf[8][264] + one shared zrow[264];
//      lanes tc>=8 read zrow via a THREAD-CONSTANT base select (no per-read
//      VALU).  32 of 64 lanes become same-address broadcasts (free, m136);
//      the rest spread 8 rows -> ~4 accesses/bank.  A-frag LDS cost ~halves
//      (~-5K cyc/CU/step of the ~25K LDS-pipe load).  Rows 8-15 contribute
//      the same zeros -> bit-identical output.
//  (2) gate-major Whh chunks (g=J>>2, kc=J&3): pump address is shift/mask
//      only (kills runtime %3,/3).  Per-gate kf order still ascending ->
//      bit-identical.
// Everything else v6 verbatim: 64 WGs x 8 rows, 16 waves, lane-rebalanced
// epilogues, wOr/wOz persistent in AGPR, VGPR+AGPR = 128 = 4 waves/SIMD cap,
// 3-slot ring, v6 vmcnt ledger (first wait<4> drains store+xg*3+chunk0;
// steady <4>; tail <2>,<0>).
// ---------------------------------------------------------------------------
__global__ __launch_bounds__(1024) void scan_fused(
    const ushort* __restrict__ XgSw,  // [32][128][768][16] bf16 swizzled
    const ushort* __restrict__ OhrP, const ushort* __restrict__ OhzP,
    const ushort* __restrict__ OhhP,  // packed N=256,K=256
    const ushort* __restrict__ WhhP,  // packed N=768,K=256
    const float*  __restrict__ bhh,   // [768]
    ushort* __restrict__ hseq)        // [65536,256] bf16, row = b*128+t
{
    const int bx = blockIdx.x;        // 64 WGs x 8 rows
    const int m0 = bx * 8;
    const int tid = threadIdx.x;
    const int w = tid >> 6, lane = tid & 63;   // 16 waves
    const int q = lane >> 4, tc = lane & 15;
    const int lo8 = lane * 8;
    const int colbase = w * 16 + tc;           // this wave's ntile = w
    const int R = ((lane >> 4) & 1) * 4 + ((lane >> 5) << 1);  // balanced row
    const bool lo = (q < 2);

    __shared__ __align__(16) ushort ring[16][3][1024];  // 96 KB (2 KB/slot)
    __shared__ __align__(16) ushort h_bf[8][264];       // 4.1 KB (valid rows)
    __shared__ __align__(16) ushort rh_bf[8][264];      // 4.1 KB
    __shared__ __align__(16) ushort zrow[264];          // shared zero row

    for (int i = tid; i < 8 * 264; i += 1024) (&h_bf[0][0])[i] = 0;
    for (int i = tid; i < 264; i += 1024) zrow[i] = 0;

    // thread-constant A-fragment base: rows 8-15 are the zero row (broadcast)
    const ushort* abase = (tc < 8) ? &h_bf[tc][0] : &zrow[0];
    const ushort* rbase = (tc < 8) ? &rh_bf[tc][0] : &zrow[0];

    // per-thread biases (1 ntile -> scalars; same for both balanced rows)
    float rbv = bhh[colbase], zbv = bhh[256 + colbase], hnbv = bhh[512 + colbase];

    // persistent ODE r/z weights, this wave's ntile: 16 frags = 64 regs
    bf16x8 wOr[8], wOz[8];
#pragma unroll
    for (int f = 0; f < 8; f++) {
        wOr[f] = *(const bf16x8*)(OhrP + (size_t)(w * 8 + f) * 512 + lo8);
        wOz[f] = *(const bf16x8*)(OhzP + (size_t)(w * 8 + f) * 512 + lo8);
    }

    float hreg[2] = {0.f, 0.f};  // balanced rows R, R+1

    int ic = 0, islot = 0, slot = 0;
    auto pump = [&]() {
        if (ic >= 28) return;
        asm volatile("s_waitcnt lgkmcnt(0)" ::: "memory");  // slot-reuse fence
        const ushort* g;
        if (ic < 16) {
            g = OhhP + (size_t)(w * 8 + (ic & 3) * 2) * 512;
        } else {
            int j = ic - 16, gg = j >> 2, kc = j & 3;   // gate-major: cheap
            g = WhhP + (size_t)((gg * 16 + w) * 8 + kc * 2) * 512;
        }
        g += lo8;
        ushort* sb = &ring[w][islot][0];
        dma16(g, sb); dma16(g + 512, sb + 512);
        ic++; islot = (islot == 2) ? 0 : islot + 1;
    };

    __syncthreads();  // zero-fill visible (no DMA yet)

#pragma unroll 1
    for (int t = 0; t < 128; t++) {
        // x-gates: 2 balanced rows per thread -> 3 x uint (rows R, R+1)
        const ushort* xgp = XgSw + (((size_t)(bx >> 1) * 128 + t) * 768) * 16
                            + (bx & 1) * 8 + R;
        uint xg[3];
#pragma unroll
        for (int g = 0; g < 3; g++)
            xg[g] = *(const uint*)(xgp + (size_t)(g * 256 + colbase) * 16);

        ic = 0; islot = 0; slot = 0;
        pump(); pump(); pump();

        // ---- 4 Euler ODE substeps ----
#pragma unroll 1
        for (int s = 0; s < 4; s++) {
            f32x4 ar = Z4, az = Z4;
#pragma unroll
            for (int kh = 0; kh < 2; kh++) {
                bf16x8 af[4];
#pragma unroll
                for (int k = 0; k < 4; k++)
                    af[k] = *(const bf16x8*)(abase + (kh * 4 + k) * 32 + q * 8);
#pragma unroll
                for (int k = 0; k < 4; k++) {
                    ar = mfma16(af[k], wOr[kh * 4 + k], ar);
                    az = mfma16(af[k], wOz[kh * 4 + k], az);
                }
            }
            // rebalance ar/az: lane>=32 takes elems {2,3} of lane-32
            float ar2 = __shfl(ar[2], lane & 31), ar3 = __shfl(ar[3], lane & 31);
            float az2 = __shfl(az[2], lane & 31), az3 = __shfl(az[3], lane & 31);
            float ea0 = lo ? ar[0] : ar2, ea1 = lo ? ar[1] : ar3;
            float ez0 = lo ? az[0] : az2, ez1 = lo ? az[1] : az3;
            rh_bf[R + 0][colbase] = f2bf(sigmoidf_(ea0) * hreg[0]);
            rh_bf[R + 1][colbase] = f2bf(sigmoidf_(ea1) * hreg[1]);
            wg_sync();  // rh ready

            f32x4 uu = Z4;
#pragma unroll
            for (int cc = 0; cc < 4; cc++) {  // chunk cc: kf pair {2cc, 2cc+1}
                bf16x8 au0 = *(const bf16x8*)(rbase + (cc * 2) * 32 + q * 8);
                bf16x8 au1 = *(const bf16x8*)(rbase + (cc * 2 + 1) * 32 + q * 8);
                ring_wait<4>();
                const ushort* sb = &ring[w][slot][0] + lo8;
                bf16x8 v0 = *(const bf16x8*)(sb);
                bf16x8 v1 = *(const bf16x8*)(sb + 512);
                slot = (slot == 2) ? 0 : slot + 1;
                pump();
                uu = mfma16(au0, v0, uu);
                uu = mfma16(au1, v1, uu);
            }
            // rebalance uu; z already balanced (ez0/ez1)
            float uu2 = __shfl(uu[2], lane & 31), uu3 = __shfl(uu[3], lane & 31);
            float eu0 = lo ? uu[0] : uu2, eu1 = lo ? uu[1] : uu3;
            {
                float zv = sigmoidf_(ez0), hv = hreg[0];
                float hn = hv + 0.25f * (1.f - zv) * (tanhf_(eu0) - hv);
                hreg[0] = hn;
                h_bf[R + 0][colbase] = f2bf(hn);
            }
            {
                float zv = sigmoidf_(ez1), hv = hreg[1];
                float hn = hv + 0.25f * (1.f - zv) * (tanhf_(eu1) - hv);
                hreg[1] = hn;
                h_bf[R + 1][colbase] = f2bf(hn);
            }
            wg_sync();  // h ready
        }

        // ---- GRU h-part: Whh, 12 chunks, gate-major (g=J>>2, kc=J&3) ----
        f32x4 accr = Z4, accz = Z4, accn = Z4;
#define GRU_CHUNK(J, WN)                                                       \
        {                                                                      \
            constexpr int g_ = (J) >> 2, kc_ = (J) & 3;                        \
            bf16x8 ah0 = *(const bf16x8*)(abase + (kc_ * 2) * 32 + q * 8);     \
            bf16x8 ah1 = *(const bf16x8*)(abase + (kc_ * 2 + 1) * 32 + q * 8); \
            ring_wait<WN>();                                                   \
            const ushort* sb = &ring[w][slot][0] + lo8;                        \
            bf16x8 v0 = *(const bf16x8*)(sb);                                  \
            bf16x8 v1 = *(const bf16x8*)(sb + 512);                            \
            slot = (slot == 2) ? 0 : slot + 1;                                 \
            pump();                                                            \
            f32x4* tg = (g_ == 0) ? &accr : (g_ == 1) ? &accz : &accn;         \
            *tg = mfma16(ah0, v0, *tg);                                        \
            *tg = mfma16(ah1, v1, *tg);                                        \
        }
        GRU_CHUNK(0, 4)  GRU_CHUNK(1, 4)  GRU_CHUNK(2, 4)  GRU_CHUNK(3, 4)
        GRU_CHUNK(4, 4)  GRU_CHUNK(5, 4)  GRU_CHUNK(6, 4)  GRU_CHUNK(7, 4)
        GRU_CHUNK(8, 4)  GRU_CHUNK(9, 4)  GRU_CHUNK(10, 2) GRU_CHUNK(11, 0)
#undef GRU_CHUNK
        wg_sync();  // all h_bf reads done

        // ---- GRU epilogue, balanced (2 elems/thread) ----
        {
            float r2 = __shfl(accr[2], lane & 31), r3 = __shfl(accr[3], lane & 31);
            float z2 = __shfl(accz[2], lane & 31), z3 = __shfl(accz[3], lane & 31);
            float n2 = __shfl(accn[2], lane & 31), n3 = __shfl(accn[3], lane & 31);
            float er0 = lo ? accr[0] : r2, er1 = lo ? accr[1] : r3;
            float ez0 = lo ? accz[0] : z2, ez1 = lo ? accz[1] : z3;
            float en0 = lo ? accn[0] : n2, en1 = lo ? accn[1] : n3;
            {
                float xr = bf2f((ushort)(xg[0])), xz = bf2f((ushort)(xg[1])),
                      xn = bf2f((ushort)(xg[2]));
                float rg = sigmoidf_(er0 + xr + rbv);
                float zg = sigmoidf_(ez0 + xz + zbv);
                float ng = tanhf_(xn + rg * (en0 + hnbv));
                float hv = hreg[0];
                float hn = (1.f - zg) * ng + zg * hv;
                hreg[0] = hn;
                h_bf[R + 0][colbase] = f2bf(hn);
            }
            {
                float xr = bf2f((ushort)(xg[0] >> 16)), xz = bf2f((ushort)(xg[1] >> 16)),
                      xn = bf2f((ushort)(xg[2] >> 16));
                float rg = sigmoidf_(er1 + xr + rbv);
                float zg = sigmoidf_(ez1 + xz + zbv);
                float ng = tanhf_(xn + rg * (en1 + hnbv));
                float hv = hreg[1];
                float hn = (1.f - zg) * ng + zg * hv;
                hreg[1] = hn;
                h_bf[R + 1][colbase] = f2bf(hn);
            }
        }
        wg_sync();  // h_new visible

        // ---- coalesced h store: 8 rows x 256 cols, 1 uint per thread ----
        {
            int row = tid >> 7, col = (tid & 127) * 2;
            *(uint*)&hseq[((size_t)(m0 + row) * 128 + t) * 256 + col] =
                *(const uint*)&h_bf[row][col];
        }
    }
}

// ---------------------------------------------------------------------------
// Launch.  Workspace 129.6 MB:
//   [0, 100663296)            Xg swizzled [32][128][768][16] bf16
//   [100663296, 134217728)    X2 [65536,256] bf16  (aliased by hseq after use)
//   [134217728, ...)          packed weights (1.44 MB)
// ---------------------------------------------------------------------------
extern "C" void kernel_launch(void* const* d_in, const int* in_sizes, int n_in,
                              void* d_out, int out_size, void* d_ws, size_t ws_size,
                              hipStream_t stream) {
    const float* H   = (const float*)d_in[0];
    const float* W1  = (const float*)d_in[2];
    const float* b1  = (const float*)d_in[3];
    const float* W2  = (const float*)d_in[4];
    const float* b2  = (const float*)d_in[5];
    const float* Ohr = (const float*)d_in[6];
    const float* Ohz = (const float*)d_in[7];
    const float* Ohh = (const float*)d_in[8];
    const float* Wih = (const float*)d_in[9];
    const float* Whh = (const float*)d_in[10];
    const float* bih = (const float*)d_in[11];
    const float* bhh = (const float*)d_in[12];
    const float* Wr  = (const float*)d_in[13];
    const float* br  = (const float*)d_in[14];
    float* out = (float*)d_out;
    char* ws = (char*)d_ws;

    ushort* Xg   = (ushort*)(ws);
    ushort* X2   = (ushort*)(ws + 100663296);
    ushort* hseq = X2;  // alias: X2 dead before scan writes hseq
    char* pk = ws + 134217728;
    ushort* W1P  = (ushort*)(pk);
    ushort* W2P  = (ushort*)(pk + 131072);
    ushort* WrP  = (ushort*)(pk + 393216);
    ushort* OhrP = (ushort*)(pk + 458752);
    ushort* OhzP = (ushort*)(pk + 589824);
    ushort* OhhP = (ushort*)(pk + 720896);
    ushort* WihP = (ushort*)(pk + 851968);
    // end at +1245184

    pack_trans_k<<<dim3(32),  256, 0, stream>>>(W1,  W1P, 512, 128);
    pack_trans_k<<<dim3(64),  256, 0, stream>>>(W2,  W2P, 256, 512);
    pack_trans_k<<<dim3(16),  256, 0, stream>>>(Wr,  WrP, 128, 256);
    pack_direct_k<<<dim3(32), 256, 0, stream>>>(Ohr, OhrP, 256, 256);
    pack_direct_k<<<dim3(32), 256, 0, stream>>>(Ohz, OhzP, 256, 256);
    pack_direct_k<<<dim3(32), 256, 0, stream>>>(Ohh, OhhP, 256, 256);
    pack_direct_k<<<dim3(96), 256, 0, stream>>>(Wih, WihP, 768, 256);
    pack_direct_k<<<dim3(96), 256, 0, stream>>>(Whh, (ushort*)(pk + 1245184), 768, 256);
    ushort* WhhP = (ushort*)(pk + 1245184);

    // Phase A: X2 = MLP(H); Xg = X2 @ Wih^T + bih (swizzled for the scan)
    mlp_kernel<<<dim3(1024), 256, 0, stream>>>(H, W1P, b1, W2P, b2, X2);
    gemm128P<<<dim3(6, 512), 256, 0, stream>>>(X2, WihP, bih, Xg, 65536, 768, 256, 2);

    // Phase B: sequential scan -> hseq (64 WGs x 8 rows, 16 waves each)
    scan_fused<<<dim3(64), 1024, 0, stream>>>(Xg, OhrP, OhzP, OhhP, WhhP, bhh, hseq);

    // Phase C: out = hseq @ Wr + br (fp32)
    gemm128P<<<dim3(1, 512), 256, 0, stream>>>(hseq, WrP, br, out, 65536, 128, 256, 1);
}

// Round 12
// 2426.634 us; speedup vs baseline: 1.1654x; 1.0404x over previous
//
#include <hip/hip_runtime.h>

typedef unsigned short ushort;
typedef unsigned int uint;
typedef __bf16 bf16x8 __attribute__((ext_vector_type(8)));
typedef ushort ushort8 __attribute__((ext_vector_type(8)));
typedef float f32x4 __attribute__((ext_vector_type(4)));
typedef uint uint2v __attribute__((ext_vector_type(2)));

#define Z4 f32x4{0.f, 0.f, 0.f, 0.f}

__device__ __forceinline__ f32x4 mfma16(bf16x8 a, bf16x8 b, f32x4 c) {
    return __builtin_amdgcn_mfma_f32_16x16x32_bf16(a, b, c, 0, 0, 0);
}
__device__ __forceinline__ float bf2f(ushort h) {
    union { uint u; float f; } v; v.u = ((uint)h) << 16; return v.f;
}
__device__ __forceinline__ ushort f2bf(float f) {  // RNE
    union { float f; uint u; } v; v.f = f;
    uint u = v.u;
    uint r = (u + 0x7fffu + ((u >> 16) & 1u)) >> 16;
    return (ushort)r;
}
__device__ __forceinline__ float sigmoidf_(float x) { return 1.f / (1.f + __expf(-x)); }
__device__ __forceinline__ float tanhf_(float x) {
    float e = __expf(2.f * x);
    return 1.f - 2.f / (e + 1.f);
}

// Lane rebalance via the OFFICIAL builtin (hazard-safe, compiler-managed):
// want r[i<32] = x0[i] (own), r[i+32] = x2[i] (x2 of lane-32).
// __builtin_amdgcn_permlane32_swap returns BOTH updated registers
// (elem0 = new vdst, elem1 = new vsrc).  In our data lanes>=32 of x0 and x2
// are EXACTLY +0.0 (C-rows 8-15 from zeroed A-rows, +0.0 acc init; IEEE
// +0.0 + (+-0.0) = +0.0), so
//   r1 = swap(x0, x2);  r2 = swap(x2, x0);  result = r1.x + r2.y
// is correct under EITHER direction of the swap:
//   dst.low<->src.high :  r1.x = 0,       r2.y = desired
//   dst.high<->src.low :  r1.x = desired, r2.y = 0
// (v9/v10 post-mortem: raw inline-asm permlane failed both operand orders
//  with run-dependent moderate corruption — wait-state hazard not inserted
//  around opaque asm; the builtin path is what m240/T12 verified.)
__device__ __forceinline__ float plbal(float x0, float x2) {
    union { float f; uint u; } a, b; a.f = x0; b.f = x2;
    uint2v r1 = __builtin_amdgcn_permlane32_swap(a.u, b.u, false, false);
    uint2v r2 = __builtin_amdgcn_permlane32_swap(b.u, a.u, false, false);
    union { uint u; float f; } o1, o2; o1.u = r1[0]; o2.u = r2[1];
    return o1.f + o2.f;
}

typedef __attribute__((address_space(1))) uint guint;
typedef __attribute__((address_space(3))) uint luint;
__device__ __forceinline__ void dma16(const ushort* g, ushort* l) {
    __builtin_amdgcn_global_load_lds((const guint*)g, (luint*)l, 16, 0, 0);
}
template <int N> __device__ __forceinline__ void ring_wait() {
    asm volatile("s_waitcnt vmcnt(%0)" ::"n"(N) : "memory");
}
// raw barrier: LDS ordering only — does NOT drain the per-wave DMA ring (vmcnt)
__device__ __forceinline__ void wg_sync() {
    asm volatile("s_waitcnt lgkmcnt(0)\n\ts_barrier" ::: "memory");
}

// ---------------------------------------------------------------------------
// Weight pre-pack, MFMA-B fragment-major: frag F = ntile*(K/32)+kf, 1 KB each.
// ---------------------------------------------------------------------------
__global__ void pack_direct_k(const float* __restrict__ src, ushort* __restrict__ dst,
                              int N, int K) {  // src row-major [N,K]
    int total = (N >> 4) * (K >> 5) * 64;
    int idx = blockIdx.x * 256 + threadIdx.x;
    if (idx >= total) return;
    int l = idx & 63, f = idx >> 6;
    int kfrags = K >> 5;
    int nt = f / kfrags, kf = f - nt * kfrags;
    int n = nt * 16 + (l & 15);
    int k0 = kf * 32 + (l >> 4) * 8;
    const float* s = src + (size_t)n * K + k0;
    ushort8 u;
#pragma unroll
    for (int j = 0; j < 8; j++) u[j] = f2bf(s[j]);
    *(ushort8*)&dst[(size_t)f * 512 + l * 8] = u;
}
__global__ void pack_trans_k(const float* __restrict__ src, ushort* __restrict__ dst,
                             int N, int K) {  // src row-major [K,N]
    int total = (N >> 4) * (K >> 5) * 64;
    int idx = blockIdx.x * 256 + threadIdx.x;
    if (idx >= total) return;
    int l = idx & 63, f = idx >> 6;
    int kfrags = K >> 5;
    int nt = f / kfrags, kf = f - nt * kfrags;
    int n = nt * 16 + (l & 15);
    int k0 = kf * 32 + (l >> 4) * 8;
    ushort8 u;
#pragma unroll
    for (int j = 0; j < 8; j++) u[j] = f2bf(src[(size_t)(k0 + j) * N + n]);
    *(ushort8*)&dst[(size_t)f * 512 + l * 8] = u;
}

// ---------------------------------------------------------------------------
// Fused MLP: X2 = relu(H@W1+b1)@W2+b2  -> bf16 [65536,256]
// ---------------------------------------------------------------------------
__global__ __launch_bounds__(256) void mlp_kernel(
    const float* __restrict__ H,     // [65536,128] fp32
    const ushort* __restrict__ W1P,  // packed N=512,K=128
    const float* __restrict__ b1,
    const ushort* __restrict__ W2P,  // packed N=256,K=512
    const float* __restrict__ b2,
    ushort* __restrict__ X2)         // [65536,256] bf16
{
    __shared__ __align__(16) ushort sH[64][136];
    __shared__ __align__(16) ushort sT[64][264];
    __shared__ float sb1[512], sb2[256];
    const int tid = threadIdx.x;
    const int w = tid >> 6, lane = tid & 63;
    const int q = lane >> 4, tc = lane & 15;
    const int lo8 = lane * 8;
    const int m0 = blockIdx.x * 64;

    {   // stage H 64x128 fp32 -> bf16
        int r = tid >> 2, c0 = (tid & 3) * 32;
        const float* src = H + (size_t)(m0 + r) * 128 + c0;
#pragma unroll
        for (int v = 0; v < 4; v++) {
            float4 a = *(const float4*)(src + v * 8);
            float4 b = *(const float4*)(src + v * 8 + 4);
            ushort8 u;
            u[0] = f2bf(a.x); u[1] = f2bf(a.y); u[2] = f2bf(a.z); u[3] = f2bf(a.w);
            u[4] = f2bf(b.x); u[5] = f2bf(b.y); u[6] = f2bf(b.z); u[7] = f2bf(b.w);
            *(ushort8*)&sH[r][c0 + v * 8] = u;
        }
    }
    for (int i = tid; i < 512; i += 256) sb1[i] = b1[i];
    if (tid < 256) sb2[tid] = b2[tid];
    __syncthreads();

    bf16x8 af[4];
#pragma unroll
    for (int kb = 0; kb < 4; kb++) af[kb] = *(const bf16x8*)&sH[w * 16 + tc][kb * 32 + q * 8];

    f32x4 accH[16];
#pragma unroll
    for (int nt = 0; nt < 16; nt++) accH[nt] = Z4;

#pragma unroll 1
    for (int half = 0; half < 2; half++) {
        __syncthreads();  // protect sT reuse across halves
#pragma unroll
        for (int j = 0; j < 16; j++) {
            int n = half * 256 + j * 16 + tc;
            const ushort* bp = W1P + (size_t)((half * 16 + j) * 4) * 512 + lo8;
            f32x4 a = Z4;
#pragma unroll
            for (int kb = 0; kb < 4; kb++)
                a = mfma16(af[kb], *(const bf16x8*)(bp + kb * 512), a);
            float bv = sb1[n];
#pragma unroll
            for (int i = 0; i < 4; i++)
                sT[w * 16 + q * 4 + i][j * 16 + tc] = f2bf(fmaxf(a[i] + bv, 0.f));
        }
        __syncthreads();

        bf16x8 a2[8];
#pragma unroll
        for (int kb = 0; kb < 8; kb++) a2[kb] = *(const bf16x8*)&sT[w * 16 + tc][kb * 32 + q * 8];
#pragma unroll
        for (int nt = 0; nt < 16; nt++) {
            const ushort* bp = W2P + (size_t)(nt * 16 + half * 8) * 512 + lo8;
#pragma unroll
            for (int kb = 0; kb < 8; kb++)
                accH[nt] = mfma16(a2[kb], *(const bf16x8*)(bp + kb * 512), accH[nt]);
        }
    }

#pragma unroll
    for (int nt = 0; nt < 16; nt++) {
        int col = nt * 16 + tc;
        float bv = sb2[col];
#pragma unroll
        for (int i = 0; i < 4; i++)
            X2[(size_t)(m0 + w * 16 + q * 4 + i) * 256 + col] = f2bf(accH[nt][i] + bv);
    }
}

// ---------------------------------------------------------------------------
// GEMM, packed-B: C = A @ B^T + bias.  A bf16 row-major [M,K], BP packed.
// mode 0: bf16 row-major out; 1: fp32 row-major out; 2: bf16 Xg-swizzle out
// ---------------------------------------------------------------------------
__global__ __launch_bounds__(256) void gemm128P(
    const ushort* __restrict__ A, const ushort* __restrict__ BP,
    const float* __restrict__ bias, void* __restrict__ Cout,
    int M, int N, int K, int mode)
{
    __shared__ __align__(16) ushort sA[128][40];
    const int tid = threadIdx.x;
    const int lane = tid & 63, wid = tid >> 6;
    const int q = lane >> 4, tc = lane & 15;
    const int lo8 = lane * 8;
    const int wm = (wid >> 1) * 64, wn = (wid & 1) * 64;
    const int bm = blockIdx.y * 128, bn = blockIdx.x * 128;

    f32x4 acc[4][4];
#pragma unroll
    for (int im = 0; im < 4; im++)
#pragma unroll
        for (int in_ = 0; in_ < 4; in_++) acc[im][in_] = Z4;

    const int arow = tid >> 1, acol = (tid & 1) * 16;
    const int kfrags = K >> 5;

    for (int kc = 0; kc < K; kc += 32) {
        const ushort* ga = A + (size_t)(bm + arow) * K + kc + acol;
        ushort8 va0 = *(const ushort8*)ga;
        ushort8 va1 = *(const ushort8*)(ga + 8);
        __syncthreads();
        *(ushort8*)&sA[arow][acol] = va0;
        *(ushort8*)&sA[arow][acol + 8] = va1;
        __syncthreads();

        bf16x8 af[4], bf[4];
#pragma unroll
        for (int im = 0; im < 4; im++) af[im] = *(const bf16x8*)&sA[wm + im * 16 + tc][q * 8];
#pragma unroll
        for (int in_ = 0; in_ < 4; in_++) {
            int nt = ((bn + wn) >> 4) + in_;
            bf[in_] = *(const bf16x8*)(BP + (size_t)(nt * kfrags + (kc >> 5)) * 512 + lo8);
        }
#pragma unroll
        for (int im = 0; im < 4; im++)
#pragma unroll
            for (int in_ = 0; in_ < 4; in_++)
                acc[im][in_] = mfma16(af[im], bf[in_], acc[im][in_]);
    }

#pragma unroll
    for (int in_ = 0; in_ < 4; in_++) {
        int col = bn + wn + in_ * 16 + tc;
        float bv = bias[col];
#pragma unroll
        for (int im = 0; im < 4; im++) {
            int row0 = bm + wm + im * 16 + q * 4;
#pragma unroll
            for (int r = 0; r < 4; r++) {
                float v = acc[im][in_][r] + bv;
                int row = row0 + r;
                if (mode == 0) {
                    ((ushort*)Cout)[(size_t)row * N + col] = f2bf(v);
                } else if (mode == 1) {
                    ((float*)Cout)[(size_t)row * N + col] = v;
                } else {
                    int b = row >> 7, t = row & 127;
                    size_t dst = (((size_t)(b >> 4) * 128 + t) * N + col) * 16 + (b & 15);
                    ((ushort*)Cout)[dst] = f2bf(v);
                }
            }
        }
    }
}

// ---------------------------------------------------------------------------
// Sequential scan, v12 = v11 resubmitted (round 11 was an infra failure —
// same "container failed twice" signature as round 3, which reran cleanly).
// v11 = v8 + BUILTIN-permlane rebalance (plbal): direction-agnostic
// construction, bit-identical values to the proven v6/v8 __shfl+select
// mapping.  Everything else v8 verbatim (64 WGs x 8 rows, 16 waves,
// zero-row broadcast A-frags, gate-major Whh pumps, 3-slot ring, v6 vmcnt
// ledger, VGPR+AGPR = 128 = 4 waves/SIMD cap).
// ---------------------------------------------------------------------------
__global__ __launch_bounds__(1024) void scan_fused(
    const ushort* __restrict__ XgSw,  // [32][128][768][16] bf16 swizzled
    const ushort* __restrict__ OhrP, const ushort* __restrict__ OhzP,
    const ushort* __restrict__ OhhP,  // packed N=256,K=256
    const ushort* __restrict__ WhhP,  // packed N=768,K=256
    const float*  __restrict__ bhh,   // [768]
    ushort* __restrict__ hseq)        // [65536,256] bf16, row = b*128+t
{
    const int bx = blockIdx.x;        // 64 WGs x 8 rows
    const int m0 = bx * 8;
    const int tid = threadIdx.x;
    const int w = tid >> 6, lane = tid & 63;   // 16 waves
    const int q = lane >> 4, tc = lane & 15;
    const int lo8 = lane * 8;
    const int colbase = w * 16 + tc;           // this wave's ntile = w
    const int R = ((lane >> 4) & 1) * 4 + ((lane >> 5) << 1);  // balanced row

    __shared__ __align__(16) ushort ring[16][3][1024];  // 96 KB (2 KB/slot)
    __shared__ __align__(16) ushort h_bf[8][264];       // 4.1 KB (valid rows)
    __shared__ __align__(16) ushort rh_bf[8][264];      // 4.1 KB
    __shared__ __align__(16) ushort zrow[264];          // shared zero row

    for (int i = tid; i < 8 * 264; i += 1024) (&h_bf[0][0])[i] = 0;
    for (int i = tid; i < 264; i += 1024) zrow[i] = 0;

    // thread-constant A-fragment base: rows 8-15 are the zero row (broadcast)
    const ushort* abase = (tc < 8) ? &h_bf[tc][0] : &zrow[0];
    const ushort* rbase = (tc < 8) ? &rh_bf[tc][0] : &zrow[0];

    // per-thread biases (1 ntile -> scalars; same for both balanced rows)
    float rbv = bhh[colbase], zbv = bhh[256 + colbase], hnbv = bhh[512 + colbase];

    // persistent ODE r/z weights, this wave's ntile: 16 frags = 64 regs
    bf16x8 wOr[8], wOz[8];
#pragma unroll
    for (int f = 0; f < 8; f++) {
        wOr[f] = *(const bf16x8*)(OhrP + (size_t)(w * 8 + f) * 512 + lo8);
        wOz[f] = *(const bf16x8*)(OhzP + (size_t)(w * 8 + f) * 512 + lo8);
    }

    float hreg[2] = {0.f, 0.f};  // balanced rows R, R+1

    int ic = 0, islot = 0, slot = 0;
    auto pump = [&]() {
        if (ic >= 28) return;
        asm volatile("s_waitcnt lgkmcnt(0)" ::: "memory");  // slot-reuse fence
        const ushort* g;
        if (ic < 16) {
            g = OhhP + (size_t)(w * 8 + (ic & 3) * 2) * 512;
        } else {
            int j = ic - 16, gg = j >> 2, kc = j & 3;   // gate-major: cheap
            g = WhhP + (size_t)((gg * 16 + w) * 8 + kc * 2) * 512;
        }
        g += lo8;
        ushort* sb = &ring[w][islot][0];
        dma16(g, sb); dma16(g + 512, sb + 512);
        ic++; islot = (islot == 2) ? 0 : islot + 1;
    };

    __syncthreads();  // zero-fill visible (no DMA yet)

#pragma unroll 1
    for (int t = 0; t < 128; t++) {
        // x-gates: 2 balanced rows per thread -> 3 x uint (rows R, R+1)
        const ushort* xgp = XgSw + (((size_t)(bx >> 1) * 128 + t) * 768) * 16
                            + (bx & 1) * 8 + R;
        uint xg[3];
#pragma unroll
        for (int g = 0; g < 3; g++)
            xg[g] = *(const uint*)(xgp + (size_t)(g * 256 + colbase) * 16);

        ic = 0; islot = 0; slot = 0;
        pump(); pump(); pump();

        // ---- 4 Euler ODE substeps ----
#pragma unroll 1
        for (int s = 0; s < 4; s++) {
            f32x4 ar = Z4, az = Z4;
#pragma unroll
            for (int kh = 0; kh < 2; kh++) {
                bf16x8 af[4];
#pragma unroll
                for (int k = 0; k < 4; k++)
                    af[k] = *(const bf16x8*)(abase + (kh * 4 + k) * 32 + q * 8);
#pragma unroll
                for (int k = 0; k < 4; k++) {
                    ar = mfma16(af[k], wOr[kh * 4 + k], ar);
                    az = mfma16(af[k], wOz[kh * 4 + k], az);
                }
            }
            // rebalance via builtin permlane (direction-agnostic plbal)
            float ea0 = plbal(ar[0], ar[2]), ea1 = plbal(ar[1], ar[3]);
            float ez0 = plbal(az[0], az[2]), ez1 = plbal(az[1], az[3]);
            rh_bf[R + 0][colbase] = f2bf(sigmoidf_(ea0) * hreg[0]);
            rh_bf[R + 1][colbase] = f2bf(sigmoidf_(ea1) * hreg[1]);
            wg_sync();  // rh ready

            f32x4 uu = Z4;
#pragma unroll
            for (int cc = 0; cc < 4; cc++) {  // chunk cc: kf pair {2cc, 2cc+1}
                bf16x8 au0 = *(const bf16x8*)(rbase + (cc * 2) * 32 + q * 8);
                bf16x8 au1 = *(const bf16x8*)(rbase + (cc * 2 + 1) * 32 + q * 8);
                ring_wait<4>();
                const ushort* sb = &ring[w][slot][0] + lo8;
                bf16x8 v0 = *(const bf16x8*)(sb);
                bf16x8 v1 = *(const bf16x8*)(sb + 512);
                slot = (slot == 2) ? 0 : slot + 1;
                pump();
                uu = mfma16(au0, v0, uu);
                uu = mfma16(au1, v1, uu);
            }
            float eu0 = plbal(uu[0], uu[2]), eu1 = plbal(uu[1], uu[3]);
            {
                float zv = sigmoidf_(ez0), hv = hreg[0];
                float hn = hv + 0.25f * (1.f - zv) * (tanhf_(eu0) - hv);
                hreg[0] = hn;
                h_bf[R + 0][colbase] = f2bf(hn);
            }
            {
                float zv = sigmoidf_(ez1), hv = hreg[1];
                float hn = hv + 0.25f * (1.f - zv) * (tanhf_(eu1) - hv);
                hreg[1] = hn;
                h_bf[R + 1][colbase] = f2bf(hn);
            }
            wg_sync();  // h ready
        }

        // ---- GRU h-part: Whh, 12 chunks, gate-major (g=J>>2, kc=J&3) ----
        f32x4 accr = Z4, accz = Z4, accn = Z4;
#define GRU_CHUNK(J, WN)                                                       \
        {                                                                      \
            constexpr int g_ = (J) >> 2, kc_ = (J) & 3;                        \
            bf16x8 ah0 = *(const bf16x8*)(abase + (kc_ * 2) * 32 + q * 8);     \
            bf16x8 ah1 = *(const bf16x8*)(abase + (kc_ * 2 + 1) * 32 + q * 8); \
            ring_wait<WN>();                                                   \
            const ushort* sb = &ring[w][slot][0] + lo8;                        \
            bf16x8 v0 = *(const bf16x8*)(sb);                                  \
            bf16x8 v1 = *(const bf16x8*)(sb + 512);                            \
            slot = (slot == 2) ? 0 : slot + 1;                                 \
            pump();                                                            \
            f32x4* tg = (g_ == 0) ? &accr : (g_ == 1) ? &accz : &accn;         \
            *tg = mfma16(ah0, v0, *tg);                                        \
            *tg = mfma16(ah1, v1, *tg);                                        \
        }
        GRU_CHUNK(0, 4)  GRU_CHUNK(1, 4)  GRU_CHUNK(2, 4)  GRU_CHUNK(3, 4)
        GRU_CHUNK(4, 4)  GRU_CHUNK(5, 4)  GRU_CHUNK(6, 4)  GRU_CHUNK(7, 4)
        GRU_CHUNK(8, 4)  GRU_CHUNK(9, 4)  GRU_CHUNK(10, 2) GRU_CHUNK(11, 0)
#undef GRU_CHUNK
        wg_sync();  // all h_bf reads done

        // ---- GRU epilogue, balanced (2 elems/thread) ----
        {
            float er0 = plbal(accr[0], accr[2]), er1 = plbal(accr[1], accr[3]);
            float ez0 = plbal(accz[0], accz[2]), ez1 = plbal(accz[1], accz[3]);
            float en0 = plbal(accn[0], accn[2]), en1 = plbal(accn[1], accn[3]);
            {
                float xr = bf2f((ushort)(xg[0])), xz = bf2f((ushort)(xg[1])),
                      xn = bf2f((ushort)(xg[2]));
                float rg = sigmoidf_(er0 + xr + rbv);
                float zg = sigmoidf_(ez0 + xz + zbv);
                float ng = tanhf_(xn + rg * (en0 + hnbv));
                float hv = hreg[0];
                float hn = (1.f - zg) * ng + zg * hv;
                hreg[0] = hn;
                h_bf[R + 0][colbase] = f2bf(hn);
            }
            {
                float xr = bf2f((ushort)(xg[0] >> 16)), xz = bf2f((ushort)(xg[1] >> 16)),
                      xn = bf2f((ushort)(xg[2] >> 16));
                float rg = sigmoidf_(er1 + xr + rbv);
                float zg = sigmoidf_(ez1 + xz + zbv);
                float ng = tanhf_(xn + rg * (en1 + hnbv));
                float hv = hreg[1];
                float hn = (1.f - zg) * ng + zg * hv;
                hreg[1] = hn;
                h_bf[R + 1][colbase] = f2bf(hn);
            }
        }
        wg_sync();  // h_new visible

        // ---- coalesced h store: 8 rows x 256 cols, 1 uint per thread ----
        {
            int row = tid >> 7, col = (tid & 127) * 2;
            *(uint*)&hseq[((size_t)(m0 + row) * 128 + t) * 256 + col] =
                *(const uint*)&h_bf[row][col];
        }
    }
}

// ---------------------------------------------------------------------------
// Launch.  Workspace 129.6 MB:
//   [0, 100663296)            Xg swizzled [32][128][768][16] bf16
//   [100663296, 134217728)    X2 [65536,256] bf16  (aliased by hseq after use)
//   [134217728, ...)          packed weights (1.44 MB)
// ---------------------------------------------------------------------------
extern "C" void kernel_launch(void* const* d_in, const int* in_sizes, int n_in,
                              void* d_out, int out_size, void* d_ws, size_t ws_size,
                              hipStream_t stream) {
    const float* H   = (const float*)d_in[0];
    const float* W1  = (const float*)d_in[2];
    const float* b1  = (const float*)d_in[3];
    const float* W2  = (const float*)d_in[4];
    const float* b2  = (const float*)d_in[5];
    const float* Ohr = (const float*)d_in[6];
    const float* Ohz = (const float*)d_in[7];
    const float* Ohh = (const float*)d_in[8];
    const float* Wih = (const float*)d_in[9];
    const float* Whh = (const float*)d_in[10];
    const float* bih = (const float*)d_in[11];
    const float* bhh = (const float*)d_in[12];
    const float* Wr  = (const float*)d_in[13];
    const float* br  = (const float*)d_in[14];
    float* out = (float*)d_out;
    char* ws = (char*)d_ws;

    ushort* Xg   = (ushort*)(ws);
    ushort* X2   = (ushort*)(ws + 100663296);
    ushort* hseq = X2;  // alias: X2 dead before scan writes hseq
    char* pk = ws + 134217728;
    ushort* W1P  = (ushort*)(pk);
    ushort* W2P  = (ushort*)(pk + 131072);
    ushort* WrP  = (ushort*)(pk + 393216);
    ushort* OhrP = (ushort*)(pk + 458752);
    ushort* OhzP = (ushort*)(pk + 589824);
    ushort* OhhP = (ushort*)(pk + 720896);
    ushort* WihP = (ushort*)(pk + 851968);
    // end at +1245184

    pack_trans_k<<<dim3(32),  256, 0, stream>>>(W1,  W1P, 512, 128);
    pack_trans_k<<<dim3(64),  256, 0, stream>>>(W2,  W2P, 256, 512);
    pack_trans_k<<<dim3(16),  256, 0, stream>>>(Wr,  WrP, 128, 256);
    pack_direct_k<<<dim3(32), 256, 0, stream>>>(Ohr, OhrP, 256, 256);
    pack_direct_k<<<dim3(32), 256, 0, stream>>>(Ohz, OhzP, 256, 256);
    pack_direct_k<<<dim3(32), 256, 0, stream>>>(Ohh, OhhP, 256, 256);
    pack_direct_k<<<dim3(96), 256, 0, stream>>>(Wih, WihP, 768, 256);
    pack_direct_k<<<dim3(96), 256, 0, stream>>>(Whh, (ushort*)(pk + 1245184), 768, 256);
    ushort* WhhP = (ushort*)(pk + 1245184);

    // Phase A: X2 = MLP(H); Xg = X2 @ Wih^T + bih (swizzled for the scan)
    mlp_kernel<<<dim3(1024), 256, 0, stream>>>(H, W1P, b1, W2P, b2, X2);
    gemm128P<<<dim3(6, 512), 256, 0, stream>>>(X2, WihP, bih, Xg, 65536, 768, 256, 2);

    // Phase B: sequential scan -> hseq (64 WGs x 8 rows, 16 waves each)
    scan_fused<<<dim3(64), 1024, 0, stream>>>(Xg, OhrP, OhzP, OhhP, WhhP, bhh, hseq);

    // Phase C: out = hseq @ Wr + br (fp32)
    gemm128P<<<dim3(1, 512), 256, 0, stream>>>(hseq, WrP, br, out, 65536, 128, 256, 1);
}